// Round 1
// baseline (432.145 us; speedup 1.0000x reference)
//
#include <hip/hip_runtime.h>

// Block-wise Hadamard transform (block = 128) of an 8192x8192 fp32 matrix.
// y = (x.reshape(-1,128) @ H).reshape(8192,8192), H = Sylvester Hadamard / sqrt(128).
// Implemented as a Fast Walsh-Hadamard Transform: 7 butterfly stages + scale.
//
// Layout: each lane owns a float4 (4 consecutive elements). A wave64 spans
// 256 consecutive floats = two 128-element blocks (lanes 0-31 / 32-63).
// FWHT bits 0-1: in-register on the float4. Bits 2-6: lane bits 0-4 ->
// __shfl_xor masks 1,2,4,8,16 (never crosses the 32-lane block boundary).

__global__ __launch_bounds__(256) void fwht128_kernel(
    const float* __restrict__ x,
    const float* __restrict__ H,
    float* __restrict__ out,
    int n4)
{
    const float s = H[0];                 // = +1/sqrt(128), uniform scalar load
    const int lane = threadIdx.x & 63;

    // Per-lane butterfly signs for the 5 shuffle stages (loop-invariant):
    // if the lane's bit is set, new = partner - mine; else new = mine + partner.
    float sgn[5];
#pragma unroll
    for (int k = 0; k < 5; ++k)
        sgn[k] = (lane & (1 << k)) ? -1.0f : 1.0f;

    const float4* __restrict__ x4 = reinterpret_cast<const float4*>(x);
    float4* __restrict__ o4 = reinterpret_cast<float4*>(out);

    for (int i = blockIdx.x * blockDim.x + threadIdx.x; i < n4;
         i += gridDim.x * blockDim.x) {
        float4 v = x4[i];

        // Stage bit 0: pairs (x,y), (z,w)
        float a = v.x + v.y;
        float b = v.x - v.y;
        float c = v.z + v.w;
        float d = v.z - v.w;
        // Stage bit 1: pairs (a,c), (b,d)
        v.x = a + c;
        v.y = b + d;
        v.z = a - c;
        v.w = b - d;

        // Stages bits 2..6: cross-lane butterflies, masks 1,2,4,8,16
#pragma unroll
        for (int k = 0; k < 5; ++k) {
            const int m = 1 << k;
            float tx = __shfl_xor(v.x, m);
            float ty = __shfl_xor(v.y, m);
            float tz = __shfl_xor(v.z, m);
            float tw = __shfl_xor(v.w, m);
            // sign=+1: v+t ; sign=-1: t-v
            v.x = fmaf(sgn[k], v.x, tx);
            v.y = fmaf(sgn[k], v.y, ty);
            v.z = fmaf(sgn[k], v.z, tz);
            v.w = fmaf(sgn[k], v.w, tw);
        }

        v.x *= s; v.y *= s; v.z *= s; v.w *= s;
        o4[i] = v;
    }
}

extern "C" void kernel_launch(void* const* d_in, const int* in_sizes, int n_in,
                              void* d_out, int out_size, void* d_ws, size_t ws_size,
                              hipStream_t stream)
{
    const float* x = (const float*)d_in[0];
    const float* H = (const float*)d_in[1];
    float* out = (float*)d_out;

    int n4 = out_size >> 2;               // 8192*8192/4 = 16,777,216 float4s
    int threads = 256;
    int blocks = 2048;                    // grid-stride; ~8 blocks/CU worth of waves
    fwht128_kernel<<<blocks, threads, 0, stream>>>(x, H, out, n4);
}